// Round 5
// baseline (86.431 us; speedup 1.0000x reference)
//
#include <hip/hip_runtime.h>
#include <math.h>

// Problem dims (fixed)
#define NN      16
#define WIDTH   64
#define TT      2048
#define NBINS   2048
#define NROWS   32768      // NN*TT
#define NELEM   2097152    // NN*WIDTH*TT
#define NBLK    512        // vq_main grid

typedef unsigned short u16;
typedef unsigned int   u32;
typedef __attribute__((ext_vector_type(8))) short short8;   // 8 bf16 (4 VGPRs)
typedef __attribute__((ext_vector_type(4))) float f32x4;

#define MFMA_BF16 __builtin_amdgcn_mfma_f32_16x16x32_bf16
#define KEYMASK   0xFFFFF800u
#define DBIAS     0.125f

__device__ __forceinline__ u16 f2bf(float f) {            // RNE f32 -> bf16 bits
    u32 u = __float_as_uint(f);
    u32 r = u + 0x7FFFu + ((u >> 16) & 1u);
    return (u16)(r >> 16);
}

// ---------------------------------------------------------------------------
// Prep: cbT = bf16(-2*cb) in MFMA-tiled layout; cbnC = ||cb||^2 + DBIAS.
// 4 threads per bin (quad-shuffle norm reduce). Also zeroes done_ctr.
// cbT chunk layout: [bin16][kc][kseg][col][8elem]; k = kc*32 + kseg*8 + i.
// ---------------------------------------------------------------------------
__global__ __launch_bounds__(256) void cbprep_k(const float* __restrict__ cb,
                                                u16* __restrict__ cbT,
                                                float* __restrict__ cbnC,
                                                u32* __restrict__ done_ctr) {
    if (blockIdx.x == 0 && threadIdx.x == 0) *done_ctr = 0;
    int g = blockIdx.x * 256 + threadIdx.x;    // grid 32 -> 8192 threads
    int b = g >> 2, q = g & 3;                 // bin, quarter (16 k each)
    const float4* p = (const float4*)(cb + (size_t)b * 64) + q * 4;
    const int base = (b >> 4) * 1024 + (b & 15) * 8;
    float s = 0.f;
#pragma unroll
    for (int c = 0; c < 2; ++c) {              // octet o = q*2 + c
        float4 v0 = p[c * 2], v1 = p[c * 2 + 1];
        s += v0.x * v0.x + v0.y * v0.y + v0.z * v0.z + v0.w * v0.w;
        s += v1.x * v1.x + v1.y * v1.y + v1.z * v1.z + v1.w * v1.w;
        short8 h = { (short)f2bf(-2.f * v0.x), (short)f2bf(-2.f * v0.y),
                     (short)f2bf(-2.f * v0.z), (short)f2bf(-2.f * v0.w),
                     (short)f2bf(-2.f * v1.x), (short)f2bf(-2.f * v1.y),
                     (short)f2bf(-2.f * v1.z), (short)f2bf(-2.f * v1.w) };
        int o = q * 2 + c;
        *(short8*)&cbT[base + (o >> 2) * 512 + (o & 3) * 128] = h;
    }
    s += __shfl_xor(s, 1, 64);
    s += __shfl_xor(s, 2, 64);
    if (q == 0) cbnC[b] = s + DBIAS;
}

// ---------------------------------------------------------------------------
// Main: block = 64 rows x all 2048 bins (16 tiles of 128). 4 waves; wave bg
// owns 32 bins of each tile, all 64 rows. B streamed from L2 via 3-deep named
// register pipeline (no barriers, no runtime indexing). MFMA computes the
// discriminant directly: C-init = cbn+DBIAS, B = -2*cb  ->  acc = d > 0.
// Argmin via sortable u32 keys (d bits | bin). LDS atomicMin cross-wave merge.
// Fused epilogue: raw-view gather + STE write + loss/fit partials.
// Last-finishing block reduces partials and writes the two scalars.
// ---------------------------------------------------------------------------
__global__ __launch_bounds__(256, 2) void vq_main_k(
    const float* __restrict__ x, const u16* __restrict__ cbT,
    const float* __restrict__ cbnC, const float* __restrict__ cb,
    float* __restrict__ out, float* __restrict__ loss_part,
    float* __restrict__ fit_part, u32* __restrict__ done_ctr) {
    // A: [t][k] bf16, 64x64, XOR-swizzled: elem = t*64 + (k ^ ((t&7)<<3))
    __shared__ __align__(16) u16 Ah[64 * 64];
    __shared__ float xnp[4][64];
    __shared__ float xnorm_s[64];
    __shared__ u32   kq_row[64];
    __shared__ float red_l[4];
    __shared__ float ss[4], ff[4];
    __shared__ int   isLast;

    const int tid  = threadIdx.x;
    const int lane = tid & 63;
    const int bg   = tid >> 6;      // wave 0..3 = bin sub-slice
    const int col  = lane & 15;
    const int kseg = lane >> 4;     // 0..3

    const int r0 = blockIdx.x * 64;   // rows r0..r0+63; row = n*2048 + t
    const int n  = r0 >> 11;
    const int t0 = r0 & 2047;

    if (tid < 64) kq_row[tid] = 0xFFFFFFFFu;

    const int fragoff = kseg * 128 + col * 8;   // within a 1KB cbT chunk

    // --- 3 named B-register sets (NO runtime indexing anywhere) ---
    short8 s0_00, s0_01, s0_10, s0_11, s1_00, s1_01, s1_10, s1_11,
           s2_00, s2_01, s2_10, s2_11;
    float  c0_0, c0_1, c1_0, c1_1, c2_0, c2_1;

#define PF(S00, S01, S10, S11, C0, C1, TILE) do {                             \
        const int _bb = (TILE) * 128 + bg * 32 + col;                         \
        const int _c16 = ((TILE) * 8 + bg * 2) * 1024 + fragoff;              \
        C0 = cbnC[_bb];  C1 = cbnC[_bb + 16];                                 \
        S00 = *(const short8*)&cbT[_c16];                                     \
        S01 = *(const short8*)&cbT[_c16 + 512];                               \
        S10 = *(const short8*)&cbT[_c16 + 1024];                              \
        S11 = *(const short8*)&cbT[_c16 + 1536];                              \
    } while (0)

    PF(s0_00, s0_01, s0_10, s0_11, c0_0, c0_1, 0);
    PF(s1_00, s1_01, s1_10, s1_11, c1_0, c1_1, 1);
    PF(s2_00, s2_01, s2_10, s2_11, c2_0, c2_1, 2);

    // ---- Stage A: x fp32 -> bf16 [t][k] swizzled; exact fp32 xnorm ----
    {
        const int t  = tid & 63;
        const int kb = tid >> 6;     // 0..3
        const float* xp = x + (size_t)n * (WIDTH * TT) + t0 + t;
        const int sw = (t & 7) << 3;
        float xs = 0.f;
#pragma unroll
        for (int it = 0; it < 8; ++it) {
            int k2 = kb * 16 + it * 2;
            float v0 = xp[(size_t)k2 * TT];
            float v1 = xp[(size_t)(k2 + 1) * TT];
            xs += v0 * v0 + v1 * v1;
            u32 pack = (u32)f2bf(v0) | ((u32)f2bf(v1) << 16);
            *(u32*)&Ah[t * 64 + (k2 ^ sw)] = pack;   // k2 even -> pair intact
        }
        xnp[kb][t] = xs;
    }
    __syncthreads();
    if (tid < 64)
        xnorm_s[tid] = xnp[0][tid] + xnp[1][tid] + xnp[2][tid] + xnp[3][tid];

    // ---- A fragments in registers (held across all 16 tiles) ----
    short8 afh[4][2];
#pragma unroll
    for (int rs = 0; rs < 4; ++rs) {
        const int rt = rs * 16 + col;
        const int sw = (rt & 7) << 3;
#pragma unroll
        for (int kc = 0; kc < 2; ++kc)
            afh[rs][kc] = *(const short8*)&Ah[rt * 64 + ((kc * 32 + kseg * 8) ^ sw)];
    }

    u32 keys[16];
#pragma unroll
    for (int i = 0; i < 16; ++i) keys[i] = 0xFFFFFFFFu;

#define CM(S00, S01, S10, S11, C0, C1, TILE) do {                             \
        const f32x4 ci0 = {C0, C0, C0, C0};                                   \
        const f32x4 ci1 = {C1, C1, C1, C1};                                   \
        const u32 bin0 = (u32)((TILE) * 128 + bg * 32 + col);                 \
        _Pragma("unroll")                                                     \
        for (int rs = 0; rs < 4; ++rs) {                                      \
            f32x4 a0 = ci0, a1 = ci1;                                         \
            a0 = MFMA_BF16(afh[rs][0], S00, a0, 0, 0, 0);                     \
            a0 = MFMA_BF16(afh[rs][1], S01, a0, 0, 0, 0);                     \
            a1 = MFMA_BF16(afh[rs][0], S10, a1, 0, 0, 0);                     \
            a1 = MFMA_BF16(afh[rs][1], S11, a1, 0, 0, 0);                     \
            _Pragma("unroll")                                                 \
            for (int jj = 0; jj < 4; ++jj) {                                  \
                u32 k0 = (__float_as_uint(a0[jj]) & KEYMASK) | bin0;          \
                u32 k1 = (__float_as_uint(a1[jj]) & KEYMASK) | (bin0 + 16u);  \
                u32 km = k0 < k1 ? k0 : k1;                                   \
                int li = rs * 4 + jj;                                         \
                keys[li] = km < keys[li] ? km : keys[li];                     \
            }                                                                 \
        }                                                                     \
    } while (0)

#define STEP(S00, S01, S10, S11, C0, C1, T) do {                              \
        CM(S00, S01, S10, S11, C0, C1, T);                                    \
        if ((T) < 13) PF(S00, S01, S10, S11, C0, C1, (T) + 3);                \
    } while (0)

    STEP(s0_00, s0_01, s0_10, s0_11, c0_0, c0_1, 0);
    STEP(s1_00, s1_01, s1_10, s1_11, c1_0, c1_1, 1);
    STEP(s2_00, s2_01, s2_10, s2_11, c2_0, c2_1, 2);
    STEP(s0_00, s0_01, s0_10, s0_11, c0_0, c0_1, 3);
    STEP(s1_00, s1_01, s1_10, s1_11, c1_0, c1_1, 4);
    STEP(s2_00, s2_01, s2_10, s2_11, c2_0, c2_1, 5);
    STEP(s0_00, s0_01, s0_10, s0_11, c0_0, c0_1, 6);
    STEP(s1_00, s1_01, s1_10, s1_11, c1_0, c1_1, 7);
    STEP(s2_00, s2_01, s2_10, s2_11, c2_0, c2_1, 8);
    STEP(s0_00, s0_01, s0_10, s0_11, c0_0, c0_1, 9);
    STEP(s1_00, s1_01, s1_10, s1_11, c1_0, c1_1, 10);
    STEP(s2_00, s2_01, s2_10, s2_11, c2_0, c2_1, 11);
    STEP(s0_00, s0_01, s0_10, s0_11, c0_0, c0_1, 12);
    STEP(s1_00, s1_01, s1_10, s1_11, c1_0, c1_1, 13);
    STEP(s2_00, s2_01, s2_10, s2_11, c2_0, c2_1, 14);
    STEP(s0_00, s0_01, s0_10, s0_11, c0_0, c0_1, 15);
#undef STEP
#undef CM
#undef PF

    // ---- issue epilogue x-read now (overlaps the reduce below) ----
    const size_t ob = (size_t)r0 * 64 + (size_t)tid * 16;
    float4 xv0 = *(const float4*)(x + ob);
    float4 xv1 = *(const float4*)(x + ob + 4);
    float4 xv2 = *(const float4*)(x + ob + 8);
    float4 xv3 = *(const float4*)(x + ob + 12);

    // ---- reduce across 16 col-lanes (u32 min = value then lowest bin) ----
#pragma unroll
    for (int m = 1; m <= 8; m <<= 1) {
#pragma unroll
        for (int i = 0; i < 16; ++i) {
            u32 ok = (u32)__shfl_xor((int)keys[i], m, 64);
            keys[i] = ok < keys[i] ? ok : keys[i];
        }
    }
    // ---- cross-wave merge via LDS atomicMin ----
    if (col == 0) {
#pragma unroll
        for (int rs = 0; rs < 4; ++rs)
#pragma unroll
            for (int jj = 0; jj < 4; ++jj)
                atomicMin(&kq_row[rs * 16 + kseg * 4 + jj], keys[rs * 4 + jj]);
    }
    __syncthreads();

    // ---- fit partial (wave 0) ----
    if (tid < 64) {
        u32 km = kq_row[tid];
        float d = __uint_as_float(km & KEYMASK) - DBIAS;
        float fv = sqrtf(fmaxf(xnorm_s[tid] + d, 0.f));
#pragma unroll
        for (int m = 32; m >= 1; m >>= 1) fv += __shfl_xor(fv, m, 64);
        if (tid == 0) fit_part[blockIdx.x] = fv;
    }

    // ---- fused epilogue: raw-view gather + STE write + loss partial ----
    const int id = (int)(kq_row[tid >> 2] & 0x7FFu);
    const float* qrow = cb + (size_t)id * 64 + (tid & 3) * 16;
    float4 q0 = *(const float4*)(qrow);
    float4 q1 = *(const float4*)(qrow + 4);
    float4 q2 = *(const float4*)(qrow + 8);
    float4 q3 = *(const float4*)(qrow + 12);
    float ls = 0.f;
#define STE(QV, XV, OFF) do {                                                 \
        float4 qo;                                                            \
        qo.x = XV.x + (QV.x - XV.x); qo.y = XV.y + (QV.y - XV.y);             \
        qo.z = XV.z + (QV.z - XV.z); qo.w = XV.w + (QV.w - XV.w);             \
        *(float4*)(out + ob + OFF) = qo;                                      \
        float dx = QV.x - XV.x, dy = QV.y - XV.y;                             \
        float dz = QV.z - XV.z, dw = QV.w - XV.w;                             \
        ls += dx * dx + dy * dy + dz * dz + dw * dw;                          \
    } while (0)
    STE(q0, xv0, 0); STE(q1, xv1, 4); STE(q2, xv2, 8); STE(q3, xv3, 12);
#undef STE
#pragma unroll
    for (int m = 32; m >= 1; m >>= 1) ls += __shfl_xor(ls, m, 64);
    if (lane == 0) red_l[bg] = ls;
    __syncthreads();
    if (tid == 0)
        loss_part[blockIdx.x] = red_l[0] + red_l[1] + red_l[2] + red_l[3];

    // ---- last-block final reduction (deterministic fixed-order sums) ----
    __threadfence();
    if (tid == 0) {
        u32 old = atomicAdd(done_ctr, 1u);
        isLast = (old == NBLK - 1) ? 1 : 0;
    }
    __syncthreads();
    if (isLast) {
        __threadfence();
        float s = 0.f, f = 0.f;
        for (int i = tid; i < NBLK; i += 256) { s += loss_part[i]; f += fit_part[i]; }
#pragma unroll
        for (int m = 32; m >= 1; m >>= 1) {
            s += __shfl_xor(s, m, 64);
            f += __shfl_xor(f, m, 64);
        }
        if (lane == 0) { ss[bg] = s; ff[bg] = f; }
        __syncthreads();
        if (tid == 0) {
            float loss_sum = ss[0] + ss[1] + ss[2] + ss[3];
            float fit_sum  = ff[0] + ff[1] + ff[2] + ff[3];
            // loss = codebook_loss + 0.25*commit_loss = 1.25 * mean((q-x)^2)
            out[NELEM]     = 1.25f * loss_sum / (float)NELEM;
            out[NELEM + 1] = fit_sum / (float)NROWS;
        }
    }
}

// ---------------------------------------------------------------------------
extern "C" void kernel_launch(void* const* d_in, const int* in_sizes, int n_in,
                              void* d_out, int out_size, void* d_ws, size_t ws_size,
                              hipStream_t stream) {
    const float* x  = (const float*)d_in[0];   // (16,64,2048) fp32
    const float* cb = (const float*)d_in[1];   // (2048,64) fp32
    float* out = (float*)d_out;                // [2097152 quantized][loss][fit]

    char* ws = (char*)d_ws;
    float* cbnC      = (float*)(ws);            // 8 KB
    u16*   cbT       = (u16*)  (ws + 8192);     // 256 KB
    float* loss_part = (float*)(ws + 270336);   // 2 KB
    float* fit_part  = (float*)(ws + 272384);   // 2 KB
    u32*   done_ctr  = (u32*)  (ws + 274432);   // 4 B

    cbprep_k<<<32,  256, 0, stream>>>(cb, cbT, cbnC, done_ctr);
    vq_main_k<<<NBLK, 256, 0, stream>>>(x, cbT, cbnC, cb, out, loss_part,
                                        fit_part, done_ctr);
}